// Round 10
// baseline (595.001 us; speedup 1.0000x reference)
//
#include <hip/hip_runtime.h>

// k-th NN distance (k=32 -> 33rd smallest, self excluded), B=16384, D=128.
// R9 resubmit (container infra failure, no signal — same pod pattern as
// R2/R4/R6; identical source): fused gram+select — 512 blocks x 32 rows,
// each block scans ALL cols. Hits -> per-lane-private LDS segments (no
// atomics, no global cand traffic); in-block 33rd-max selection writes out[]
// directly. Zero barriers in K-loop. k_select eliminated; counts[] is
// per-row total (0xFFFFFFFF = overflow).

typedef unsigned short u16;
typedef unsigned int   u32;
typedef __attribute__((ext_vector_type(8))) u16    ushort8;
typedef __attribute__((ext_vector_type(8))) __bf16 bf16x8;
typedef __attribute__((ext_vector_type(4))) float  f32x4;

#define NB   16384
#define ND   128
#define SCAP 32           // slots per lane-segment (lambda~9, huge margin)
#define NTH  33           // 33rd smallest
#define ZWH  (-2.62f)     // WH quantile z: p~0.0044 -> ~72 cands/row
#define NEGF (-3.0e38f)
#define POSF ( 3.0e38f)
#define BADC 0xFFFFFFFFu

// ---- workspace layout (bytes), total ~4.4 MB ----
#define OFF_X    ((size_t)0)
#define OFF_NORM (OFF_X    + (size_t)NB * ND * 2)
#define OFF_TACC (OFF_NORM + (size_t)NB * 4)
#define OFF_XBAR (OFF_TACC + (size_t)NB * 4)
#define OFF_SCAL (OFF_XBAR + 512)
#define OFF_CNTS (OFF_SCAL + 256)

static __device__ __forceinline__ u16 f2bf(float f) {
  u32 u = __float_as_uint(f);
  u32 r = u + 0x7FFFu + ((u >> 16) & 1u);
  return (u16)(r >> 16);
}
static __device__ __forceinline__ float bf2f(u16 h) {
  return __uint_as_float(((u32)h) << 16);
}

// ---------------- K1: bf16 convert + norms (+ zero stat accumulators) ----
__global__ void k_prep(const float* __restrict__ x, u16* __restrict__ X,
                       float* __restrict__ norms, float* xbar, float* scal) {
  if (blockIdx.x == 0) {
    int tt = threadIdx.x;
    if (tt < 128) xbar[tt] = 0.f;
    if (tt < 2)   scal[tt] = 0.f;
  }
  int w = threadIdx.x >> 6, l = threadIdx.x & 63;
  int r = blockIdx.x * 4 + w;  // grid 4096
  const float2* xr2 = (const float2*)(x + (size_t)r * ND);
  float2 a = xr2[l];
  u16 h0 = f2bf(a.x), h1 = f2bf(a.y);
  float b0 = bf2f(h0), b1 = bf2f(h1);
  float n = b0 * b0 + b1 * b1;
#pragma unroll
  for (int off = 1; off < 64; off <<= 1) n += __shfl_xor(n, off, 64);
  *(u32*)(X + (size_t)r * ND + 2 * l) = (u32)h0 | ((u32)h1 << 16);
  if (l == 0) norms[r] = n;
}

// ---------------- K2: column sums (x-bar) + sum(n), sum(n^2) -------------
__global__ void k_stats(const u16* __restrict__ X, const float* __restrict__ norms,
                        float* xbar, float* scal) {
  __shared__ float xs[16][128];
  __shared__ float red1[256], red2[256];
  int t = threadIdx.x;
  int cg = t & 15;          // col-group: cols cg*8 .. cg*8+7
  int rs = t >> 4;          // row-sub 0..15
  int rbase = blockIdx.x * 256;  // grid 64
  float s[8] = {0.f, 0.f, 0.f, 0.f, 0.f, 0.f, 0.f, 0.f};
  for (int rr = 0; rr < 16; ++rr) {
    int row = rbase + rs + rr * 16;
    ushort8 v = *(const ushort8*)(X + (size_t)row * ND + cg * 8);
#pragma unroll
    for (int u = 0; u < 8; ++u) s[u] += bf2f(v[u]);
  }
#pragma unroll
  for (int u = 0; u < 8; ++u) xs[rs][cg * 8 + u] = s[u];
  float ln = norms[rbase + t];
  red1[t] = ln; red2[t] = ln * ln;
  __syncthreads();
  if (t < 128) {
    float a = 0.f;
    for (int rsub = 0; rsub < 16; ++rsub) a += xs[rsub][t];
    atomicAdd(&xbar[t], a);
  }
  for (int st = 128; st > 0; st >>= 1) {
    if (t < st) { red1[t] += red1[t + st]; red2[t] += red2[t + st]; }
    __syncthreads();
  }
  if (t == 0) { atomicAdd(&scal[0], red1[0]); atomicAdd(&scal[1], red2[0]); }
}

// ---------------- K3: per-row threshold via Wilson-Hilferty chi^2 --------
__global__ void k_thresh(const u16* __restrict__ X, const float* __restrict__ norms,
                         const float* __restrict__ xbar, const float* __restrict__ scal,
                         float* __restrict__ tacc) {
  __shared__ float xb[128];
  int t = threadIdx.x;
  if (t < 128) xb[t] = xbar[t] * (1.0f / NB);
  __syncthreads();
  int r = blockIdx.x * 256 + t;  // grid 64
  float n = norms[r];
  const u16* xr = X + (size_t)r * ND;
  float dot = 0.f;
#pragma unroll
  for (int c8 = 0; c8 < 16; ++c8) {
    ushort8 v = *(const ushort8*)(xr + c8 * 8);
#pragma unroll
    for (int j = 0; j < 8; ++j) dot += bf2f(v[j]) * xb[c8 * 8 + j];
  }
  float nbar = scal[0] * (1.0f / NB);
  float Vn = fmaxf(scal[1] * (1.0f / NB) - nbar * nbar, 0.f);
  float m = n + nbar - 2.f * dot;             // exact E_j[sq_rj]
  float v = Vn + 4.f * n * (nbar / ND);       // Var_j[sq_rj] model
  float nu = 2.f * m * m / v;
  float cc = v / (2.f * m);
  float a1 = 2.f / (9.f * nu);
  float inner = 1.f - a1 + ZWH * sqrtf(a1);
  float tsq = cc * nu * inner * inner * inner;
  tacc[r] = 0.5f * (n - tsq);   // val = acc - nc/2 >= tacc  <=>  sq <= tsq
}

// ---------------- K4: fused MFMA gram + filter + in-block selection ------
// 512 blocks x 32 rows; each block streams ALL 16384 cols (128 iters).
// 4 waves as (wr=row-half 2) x (wc=col-half 2): wave tile 16 rows x 64 cols.
// Each lane owns ONE LDS segment: row lm (of its wr half), writer (wc,lq).
// No atomics, no K-loop barriers. One barrier, then in-block selection.
__global__ __launch_bounds__(256) void k_gram(
    const u16* __restrict__ X, const float* __restrict__ norms,
    const float* __restrict__ tacc, u32* __restrict__ counts,
    float* __restrict__ out) {
  __shared__ float candL[256 * SCAP];          // 32 KB, segment = lane
  __shared__ u32 cntS[256];
  const int r0 = blockIdx.x * 32;
  const int t = threadIdx.x, w = t >> 6, l = t & 63;
  const int wr = w & 1, wc = w >> 1;
  const int lm = l & 15, lq = l >> 4;
  const int koff = lq * 8;

  // B fragments (16 owned rows) in registers
  const int myrow = r0 + wr * 16 + lm;
  bf16x8 bfrag[4];
#pragma unroll
  for (int k = 0; k < 4; ++k)
    bfrag[k] = __builtin_bit_cast(bf16x8, *(const ushort8*)(
        X + (size_t)myrow * ND + k * 32 + koff));
  const float tj = tacc[myrow];

  u32 cnt = 0;
  const int segbase = t * SCAP;
  const int it_dg = r0 >> 7;   // the one col-iter containing own rows

  // per-lane A base: col-entity (wc*64 + lm), k-chunk koff
  const u16* abase = X + (size_t)(wc * 64 + lm) * ND + koff;

  for (int it = 0; it < 128; ++it) {
    const int c0 = it * 128;
    const u16* ait = abase + (size_t)c0 * ND;

    f32x4 acc[4];
#pragma unroll
    for (int i = 0; i < 4; ++i) acc[i] = (f32x4){0.f, 0.f, 0.f, 0.f};

#pragma unroll
    for (int k = 0; k < 4; ++k) {
      bf16x8 af[4];
#pragma unroll
      for (int i = 0; i < 4; ++i)
        af[i] = __builtin_bit_cast(bf16x8, *(const ushort8*)(
            ait + (size_t)(i * 16) * ND + k * 32));
#pragma unroll
      for (int i = 0; i < 4; ++i)
        acc[i] = __builtin_amdgcn_mfma_f32_16x16x32_bf16(af[i], bfrag[k], acc[i], 0, 0, 0);
    }

    if (it != it_dg) {
#pragma unroll
      for (int i = 0; i < 4; ++i) {
        f32x4 nch = *(const f32x4*)(norms + c0 + wc * 64 + i * 16 + lq * 4);
        f32x4 val = acc[i] - nch * 0.5f;       // = x_c.x_r - n_c/2
        float g01 = fmaxf(val[0], val[1]);
        float g23 = fmaxf(val[2], val[3]);
        if (fmaxf(g01, g23) >= tj) {           // rare branch
#pragma unroll
          for (int v = 0; v < 4; ++v) {
            if (val[v] >= tj) {
              if (cnt < SCAP) candL[segbase + cnt] = val[v];
              cnt++;
            }
          }
        }
      }
    } else {                                   // diagonal tile: exclude self
#pragma unroll
      for (int i = 0; i < 4; ++i) {
        f32x4 nch = *(const f32x4*)(norms + c0 + wc * 64 + i * 16 + lq * 4);
        f32x4 val = acc[i] - nch * 0.5f;
        float g01 = fmaxf(val[0], val[1]);
        float g23 = fmaxf(val[2], val[3]);
        if (fmaxf(g01, g23) >= tj) {
#pragma unroll
          for (int v = 0; v < 4; ++v) {
            bool p = (val[v] >= tj) && ((c0 + wc * 64 + i * 16 + lq * 4 + v) != myrow);
            if (p) {
              if (cnt < SCAP) candL[segbase + cnt] = val[v];
              cnt++;
            }
          }
        }
      }
    }
  }

  cntS[t] = cnt;
  __syncthreads();

  // ---- in-block selection: wave w handles local rows w*8 .. w*8+7 ----
  for (int rr = 0; rr < 8; ++rr) {
    const int lr = w * 8 + rr;            // local row 0..31
    const int wrr = lr >> 4, lmr = lr & 15;
    const int gr = r0 + lr;
    // 8 segments of this row: sid = (wrr + 2*wc')*64 + lq'*16 + lmr
    u32 c8 = 0;
    if (l < 8) {
      int sid = (wrr + 2 * (l >> 2)) * 64 + (l & 3) * 16 + lmr;
      c8 = cntS[sid];
    }
    u32 tot = c8, mx = c8;
#pragma unroll
    for (int off = 1; off < 8; off <<= 1) {
      tot += __shfl_xor(tot, off, 64);
      u32 o = (u32)__shfl_xor((int)mx, off, 64);
      mx = mx > o ? mx : o;
    }
    tot = __shfl(tot, 0, 64);
    mx  = (u32)__shfl((int)mx, 0, 64);

    if (tot < NTH || mx > SCAP) {
      if (l == 0) counts[gr] = BADC;      // fallback owns this row
      continue;
    }
    if (l == 0) counts[gr] = tot;

    float v0, v1, v2, v3;
#define LOADV(e, dst)                                                   \
    {                                                                   \
      int s = l + 64 * e;                                               \
      int segr = s >> 5, si = s & 31;                                   \
      int sid = (wrr + 2 * (segr >> 2)) * 64 + (segr & 3) * 16 + lmr;   \
      u32 c = cntS[sid];                                                \
      dst = ((u32)si < c) ? candL[sid * SCAP + si] : NEGF;              \
    }
    LOADV(0, v0) LOADV(1, v1) LOADV(2, v2) LOADV(3, v3)
#undef LOADV

    float last = NEGF;
    for (int e = 0; e < NTH; ++e) {       // bigger val = closer
      float m = fmaxf(fmaxf(v0, v1), fmaxf(v2, v3));
#pragma unroll
      for (int off = 1; off < 64; off <<= 1) m = fmaxf(m, __shfl_xor(m, off, 64));
      bool mine = (v0 == m) || (v1 == m) || (v2 == m) || (v3 == m);
      unsigned long long bal = __ballot(mine);
      int owner = __ffsll(bal) - 1;
      if (l == owner) {
        if      (v0 == m) v0 = NEGF;
        else if (v1 == m) v1 = NEGF;
        else if (v2 == m) v2 = NEGF;
        else              v3 = NEGF;
      }
      last = m;
    }
    if (l == 0)
      out[gr] = sqrtf(fmaxf(norms[gr] - 2.f * last, 0.f));  // sq = n_r - 2*val
  }
}

// ---------------- K5: exact brute-force fallback (expected ~0 rows) -------
__global__ void k_fallback(const u32* __restrict__ counts, const u16* __restrict__ X,
                           const float* __restrict__ norms, float* __restrict__ out) {
  __shared__ float sq[NB];     // 64 KB
  __shared__ float xr[ND];
  __shared__ float rmin[256];
  __shared__ int   ridx[256];
  __shared__ int   nbad;
  __shared__ int   badlist[256];
  int t = threadIdx.x;
  if (t == 0) nbad = 0;
  __syncthreads();
  int r = blockIdx.x * 256 + t;   // grid 64: covers NB exactly
  u32 tot = counts[r];
  if (tot < NTH || tot == BADC) { int p = atomicAdd(&nbad, 1); badlist[p] = r; }
  __syncthreads();
  int nb = nbad;
  for (int ii = 0; ii < nb; ++ii) {
    int rr = badlist[ii];
    if (t < 128) xr[t] = bf2f(X[(size_t)rr * ND + t]);
    __syncthreads();
    float n_r = norms[rr];
    for (int jj = 0; jj < 64; ++jj) {
      int j = t + 256 * jj;
      const u16* xj = X + (size_t)j * ND;
      float dot = 0.f;
#pragma unroll
      for (int c8 = 0; c8 < 16; ++c8) {
        ushort8 vv = *(const ushort8*)(xj + c8 * 8);
#pragma unroll
        for (int u = 0; u < 8; ++u) dot += bf2f(vv[u]) * xr[c8 * 8 + u];
      }
      sq[j] = (j == rr) ? POSF : fmaxf(n_r + norms[j] - 2.f * dot, 0.f);
    }
    __syncthreads();
    float last = 0.f;
    for (int e = 0; e < NTH; ++e) {
      float lm = POSF; int li = -1;
      for (int jj = 0; jj < 64; ++jj) {
        int j = t + 256 * jj;
        float s = sq[j];
        if (s < lm) { lm = s; li = j; }
      }
      rmin[t] = lm; ridx[t] = li;
      __syncthreads();
      if (t == 0) {
        float gm = POSF; int gi = -1;
        for (int u = 0; u < 256; ++u)
          if (rmin[u] < gm) { gm = rmin[u]; gi = ridx[u]; }
        sq[gi] = POSF;
        rmin[0] = gm;
      }
      __syncthreads();
      last = rmin[0];
      __syncthreads();
    }
    if (t == 0) out[rr] = sqrtf(fmaxf(last, 0.f));
    __syncthreads();
  }
}

extern "C" void kernel_launch(void* const* d_in, const int* in_sizes, int n_in,
                              void* d_out, int out_size, void* d_ws, size_t ws_size,
                              hipStream_t stream) {
  const float* x = (const float*)d_in[0];
  float* out = (float*)d_out;
  char* ws = (char*)d_ws;
  u16*   X     = (u16*)  (ws + OFF_X);
  float* norms = (float*)(ws + OFF_NORM);
  float* tacc  = (float*)(ws + OFF_TACC);
  float* xbar  = (float*)(ws + OFF_XBAR);
  float* scal  = (float*)(ws + OFF_SCAL);
  u32*   cnts  = (u32*)  (ws + OFF_CNTS);

  k_prep    <<<4096, 256, 0, stream>>>(x, X, norms, xbar, scal);
  k_stats   <<<64,   256, 0, stream>>>(X, norms, xbar, scal);
  k_thresh  <<<64,   256, 0, stream>>>(X, norms, xbar, scal, tacc);
  k_gram    <<<512,  256, 0, stream>>>(X, norms, tacc, cnts, out);
  k_fallback<<<64,   256, 0, stream>>>(cnts, X, norms, out);
}